// Round 1
// baseline (1406.035 us; speedup 1.0000x reference)
//
#include <hip/hip_runtime.h>
#include <math.h>

#define MB 256
#define RD 1025   // in_dim + 1 (bias row)
#define CD 1024   // out_dim

typedef float f4 __attribute__((ext_vector_type(4)));
typedef float f2 __attribute__((ext_vector_type(2)));

// ---------------------------------------------------------------------------
// Main kernel: h[b,o] = sum_i a_i*mu[i,o] + sc[o] * sum_i (a_i*sr_i)*E[b,i,o]
// One block per batch sample b. 256 threads x float4 = 1024 outputs.
// E (1.07 GB) is streamed once via nontemporal dwordx4; mu re-reads hit L2/L3.
// ---------------------------------------------------------------------------
__global__ __launch_bounds__(256) void vmg_main(
    const float* __restrict__ x,      // (256, 1024)
    const float* __restrict__ mu,     // (1025, 1024)
    const float* __restrict__ lvin,   // (1025,)
    const float* __restrict__ lvout,  // (1024,)
    const float* __restrict__ E,      // (256, 1025, 1024)
    float* __restrict__ out)          // h at [0, 262144)
{
    __shared__ f2 ay[RD];             // {a_i, a_i * sqrt(exp(lvin_i))}
    const int b   = blockIdx.x;
    const int tid = threadIdx.x;

    // Stage per-row scalars (bias row i=RD-1 has a=1).
    for (int i = tid; i < RD; i += 256) {
        float a  = (i < RD - 1) ? x[b * (RD - 1) + i] : 1.0f;
        float sr = sqrtf(expf(lvin[i]));
        f2 t; t.x = a; t.y = a * sr;
        ay[i] = t;
    }
    __syncthreads();

    const int o = tid << 2;           // 0..1020, contiguous float4 per thread
    const f4* __restrict__ Ep = (const f4*)(E + ((size_t)b * RD) * CD + o);
    const f4* __restrict__ Mp = (const f4*)(mu + o);

    f4 accM = (f4)0.0f;
    f4 accE = (f4)0.0f;

#pragma unroll 8
    for (int i = 0; i < RD; ++i) {
        f2 av = ay[i];                         // LDS broadcast (ds_read_b64)
        f4 mv = Mp[i * (CD / 4)];              // L2/L3-resident
        f4 ev = __builtin_nontemporal_load(Ep + i * (CD / 4));  // HBM stream
        accM += av.x * mv;
        accE += av.y * ev;
    }

    f4 lvo = *(const f4*)(lvout + o);
    f4 sc;
    for (int k = 0; k < 4; ++k) sc[k] = sqrtf(expf(lvo[k]));
    f4 h = accM + sc * accE;
    *(f4*)(out + (size_t)b * CD + o) = h;
}

// ---------------------------------------------------------------------------
// D_KL part 1: logvar-derived terms. Single block; WRITES (not adds) the
// scalar slot, overwriting the 0xAA poison. Must run before vmg_dkl_mu2.
// ---------------------------------------------------------------------------
__global__ __launch_bounds__(256) void vmg_dkl_base(
    const float* __restrict__ lvin,
    const float* __restrict__ lvout,
    float* __restrict__ out)
{
    const int tid = threadIdx.x;
    float svr = 0.f, slr = 0.f, svc = 0.f, slc = 0.f;
    for (int i = tid; i < RD; i += 256) { float v = lvin[i];  svr += expf(v); slr += v; }
    for (int i = tid; i < CD; i += 256) { float v = lvout[i]; svc += expf(v); slc += v; }

    for (int off = 32; off; off >>= 1) {
        svr += __shfl_down(svr, off, 64);
        slr += __shfl_down(slr, off, 64);
        svc += __shfl_down(svc, off, 64);
        slc += __shfl_down(slc, off, 64);
    }
    __shared__ float s[4][4];
    const int wave = tid >> 6, lane = tid & 63;
    if (lane == 0) { s[0][wave] = svr; s[1][wave] = slr; s[2][wave] = svc; s[3][wave] = slc; }
    __syncthreads();
    if (tid == 0) {
        float SVR = 0.f, SLR = 0.f, SVC = 0.f, SLC = 0.f;
        for (int w = 0; w < 4; ++w) { SVR += s[0][w]; SLR += s[1][w]; SVC += s[2][w]; SLC += s[3][w]; }
        out[MB * CD] = 0.5f * (SVR * SVC - (float)(RD * CD)
                               - (float)CD * SLR - (float)RD * SLC);
    }
}

// ---------------------------------------------------------------------------
// D_KL part 2: 0.5 * sum(mu^2), grid reduction + one atomicAdd per block.
// ---------------------------------------------------------------------------
__global__ __launch_bounds__(256) void vmg_dkl_mu2(
    const float* __restrict__ mu,
    float* __restrict__ out)
{
    const int n4 = (RD * CD) / 4;     // 262400, exact
    const f4* __restrict__ m4 = (const f4*)mu;
    float s = 0.f;
    for (int i = blockIdx.x * 256 + threadIdx.x; i < n4; i += gridDim.x * 256) {
        f4 v = m4[i];
        s += v.x * v.x + v.y * v.y + v.z * v.z + v.w * v.w;
    }
    for (int off = 32; off; off >>= 1) s += __shfl_down(s, off, 64);
    __shared__ float sh[4];
    const int wave = threadIdx.x >> 6, lane = threadIdx.x & 63;
    if (lane == 0) sh[wave] = s;
    __syncthreads();
    if (threadIdx.x == 0) {
        atomicAdd(out + MB * CD, 0.5f * (sh[0] + sh[1] + sh[2] + sh[3]));
    }
}

extern "C" void kernel_launch(void* const* d_in, const int* in_sizes, int n_in,
                              void* d_out, int out_size, void* d_ws, size_t ws_size,
                              hipStream_t stream) {
    const float* x     = (const float*)d_in[0];
    const float* mu    = (const float*)d_in[1];
    const float* lvin  = (const float*)d_in[2];
    const float* lvout = (const float*)d_in[3];
    const float* E     = (const float*)d_in[4];
    float* out = (float*)d_out;

    // Stream order: base (writes scalar) -> mu2 (atomic adds) -> main (h).
    vmg_dkl_base<<<1, 256, 0, stream>>>(lvin, lvout, out);
    vmg_dkl_mu2<<<128, 256, 0, stream>>>(mu, out);
    vmg_main<<<MB, 256, 0, stream>>>(x, mu, lvin, lvout, E, out);
}